// Round 14
// baseline (172.363 us; speedup 1.0000x reference)
//
#include <hip/hip_runtime.h>
#include <math.h>

// GAT forward: B=32 N=256 F=300(pad 320) O=256 H=8 OUT=512

typedef _Float16 f16;
typedef __attribute__((ext_vector_type(8))) _Float16 f16x8;
typedef __attribute__((ext_vector_type(4))) _Float16 f16x4;
typedef __attribute__((ext_vector_type(4))) float f32x4;
typedef unsigned long long u64;

__device__ __forceinline__ void async16(const void* g, void* lds) {
  __builtin_amdgcn_global_load_lds(
      (const __attribute__((address_space(1))) void*)g,
      (__attribute__((address_space(3))) void*)lds, 16, 0, 0);
}

// ---------------- fused prep: x16 + WcT + WoT + e-zero + adj bit-pack + wo12 ----------------
// [0,1280): x16; [1280,1920): WcT + e-zero; [1920,2944): WoT; [2944,3072): adjG;
// [3072,3080): wo12 (wo1[k] = sum_o2 Wo[k][o2]*ao[o2], wo2 with ao[512+o2]).
__global__ __launch_bounds__(256) void k_prep(const int* __restrict__ fea,
                                              const float* __restrict__ embed,
                                              const float* __restrict__ Whd,
                                              const float* __restrict__ Wo,
                                              const int* __restrict__ adj,
                                              const float* __restrict__ ao,
                                              f16* __restrict__ x16,
                                              f16* __restrict__ WcT,
                                              f16* __restrict__ WoT,
                                              float* __restrict__ e_all,
                                              u64* __restrict__ adjG,
                                              float* __restrict__ wo12G) {
  int bid = blockIdx.x, tid = threadIdx.x;
  if (bid < 1280) {
    // x16: 8192 rows x 40 chunks of 8 f16 (16B store per thread); float4 loads
    int idx = bid * 256 + tid;          // < 327680
    int row = idx / 40, c = idx % 40;
    int tok = fea[row];
    const float* eb = embed + (size_t)tok * 300;
    f16x8 v;
    if (c < 37) {
      float4 f0 = *(const float4*)&eb[c * 8];
      float4 f1 = *(const float4*)&eb[c * 8 + 4];
      v[0] = (f16)f0.x; v[1] = (f16)f0.y; v[2] = (f16)f0.z; v[3] = (f16)f0.w;
      v[4] = (f16)f1.x; v[5] = (f16)f1.y; v[6] = (f16)f1.z; v[7] = (f16)f1.w;
    } else {
#pragma unroll
      for (int j = 0; j < 8; ++j) {
        int t = c * 8 + j;
        v[j] = (f16)((t < 300) ? eb[t] : 0.f);
      }
    }
    *(f16x8*)&x16[(size_t)row * 320 + c * 8] = v;
  } else if (bid < 1920) {
    int r = bid - 1280;                 // < 640
    // zero e12/e22 accumulators (16384 floats, contiguous)
    int zi = r * 256 + tid;
    if (zi < 16384) e_all[zi] = 0.f;
    // WcT: W[h][t<300][o<256] -> WcT[(h*256+o)*320 + t]
    __shared__ float tile[32][33];
    int bx = r % 10, q0 = r / 10;
    int by = q0 % 8, h = q0 / 8;
    int c = tid & 31, q = tid >> 5;
#pragma unroll
    for (int i = 0; i < 4; ++i) {
      int tt = q + i * 8;
      int t = bx * 32 + tt;
      float v = (t < 300) ? Whd[((size_t)h * 300 + t) * 256 + by * 32 + c] : 0.f;
      tile[tt][c] = v;
    }
    __syncthreads();
#pragma unroll
    for (int i = 0; i < 4; ++i) {
      int oo = q + i * 8;
      int gc = h * 256 + by * 32 + oo;
      WcT[(size_t)gc * 320 + bx * 32 + c] = (f16)tile[c][oo];
    }
  } else if (bid < 2944) {
    int r = bid - 1920;                 // < 1024
    // WoT: W[k<2048][o2<512] -> WoT[o2*2048 + k]
    __shared__ float tile[32][33];
    int bx = r % 64, by = r / 64;
    int c = tid & 31, q = tid >> 5;
#pragma unroll
    for (int i = 0; i < 4; ++i) {
      int kk = q + i * 8;
      tile[kk][c] = Wo[((size_t)bx * 32 + kk) * 512 + by * 32 + c];
    }
    __syncthreads();
#pragma unroll
    for (int i = 0; i < 4; ++i) {
      int oo = q + i * 8;
      WoT[((size_t)by * 32 + oo) * 2048 + bx * 32 + c] = (f16)tile[c][oo];
    }
  } else if (bid < 3072) {
    // adjG: adj[8192 rows][256] int -> 4 u64 bitmasks per row
    int r = bid - 2944;                 // < 128
    int wv = tid >> 6, ln = tid & 63;
    int row = r * 64 + wv * 16;
    const int* ar = adj + (size_t)row * 256;
#pragma unroll 4
    for (int i = 0; i < 16; ++i, ar += 256) {
      u64 m0 = __ballot(ar[ln] != 0);
      u64 m1 = __ballot(ar[64 + ln] != 0);
      u64 m2 = __ballot(ar[128 + ln] != 0);
      u64 m3 = __ballot(ar[192 + ln] != 0);
      if (ln == 0) {
        u64* d = &adjG[(size_t)(row + i) * 4];
        d[0] = m0; d[1] = m1; d[2] = m2; d[3] = m3;
      }
    }
  } else {
    // wo12: wo1[k] = Wo[k,:] . ao[:512]; wo2[k] = Wo[k,:] . ao[512:]
    int r = bid - 3072;                 // < 8
    __shared__ float a1s[512], a2s[512];
    a1s[tid] = ao[tid];       a1s[256 + tid] = ao[256 + tid];
    a2s[tid] = ao[512 + tid]; a2s[256 + tid] = ao[768 + tid];
    __syncthreads();
    int k = r * 256 + tid;    // < 2048
    const float* wr = Wo + (size_t)k * 512;
    float s1 = 0.f, s2 = 0.f;
#pragma unroll 4
    for (int o = 0; o < 512; o += 4) {
      float4 w4 = *(const float4*)&wr[o];
      s1 += w4.x * a1s[o] + w4.y * a1s[o + 1] + w4.z * a1s[o + 2] + w4.w * a1s[o + 3];
      s2 += w4.x * a2s[o] + w4.y * a2s[o + 1] + w4.z * a2s[o + 2] + w4.w * a2s[o + 3];
    }
    wo12G[k] = s1;
    wo12G[2048 + k] = s2;
  }
}

// ---------------- fused layer 1: GEMM1 + e-dots + reg-softmax + PV + elu + e12/e22 dots ----------------
// One block per (b,h); 512 threads (8 waves); dynamic LDS 143360 B; 1 block/CU.
// Phase 2 is barrier-free: P lives in registers in MFMA B-fragment layout.
// NEW: e12/e22 partial dots (h1 . wo12 slice for this h) fused into the PV epilogue
// (linearity trick, layer-2 analog of R9's validated w12) -> gemm loses its e-epilogue.
__global__ __launch_bounds__(512, 1) void k_l1(
    const f16* __restrict__ x16, const f16* __restrict__ WcT,
    const float* __restrict__ ah, const u64* __restrict__ adjG,
    const float* __restrict__ npm, const float* __restrict__ wo12G,
    f16* __restrict__ h1, float* __restrict__ e12G, float* __restrict__ e22G) {
  extern __shared__ __align__(16) char smem[];
  f16* AsB[2] = {(f16*)smem, (f16*)(smem + 65536)};           // [256][64] each
  f16* BsB[2] = {(f16*)(smem + 32768), (f16*)(smem + 98304)}; // [256][64] each
  char* WhB = smem;                           // Wh bytes: [o][256 f16] chunk-swz
  u64* adjB = (u64*)(smem + 131072);          // [256][4]
  float* e1f = (float*)(smem + 139264);       // [256]
  float* e2f = (float*)(smem + 140288);       // [256]
  float* wol = (float*)(smem + 141312);       // [512] wo1|wo2 slice for this h

  const int bid = blockIdx.x;
  const int h = (bid >> 3) & 7;
  const int b = (bid & 7) * 4 + (bid >> 6);
  const int tid = threadIdx.x;
  const int wave = tid >> 6, lane = tid & 63;
  const int wm = wave >> 2, wn = wave & 3;
  const int lrow = lane & 15, quad = lane >> 4;
  const int srow = lane >> 3;
  const int scol = ((lane & 7) ^ (lane >> 3)) * 8;
  const int l7 = lrow & 7;

  if (tid < 256) e1f[tid] = 0.f;
  else e2f[tid - 256] = 0.f;

  // ---- phase 1: Wh = x16[b] @ WcT[h]^T into registers (2-stage dbuf) ----
  f32x4 acc[8][4] = {};   // n = wm*128+mt*16+quad*4+r ; o = wn*64+nt*16+lrow
  const f16* Ag = x16 + (size_t)b * 256 * 320;
  const f16* Bg = WcT + (size_t)h * 256 * 320;

  // prologue: stage K-step 0 into buf 0 + adjB (8KB) + wo12 slice (2KB)
  async16((const char*)adjG + (size_t)b * 8192 + tid * 16, (char*)adjB + tid * 16);
  if (tid < 64)
    async16((const char*)wo12G + (size_t)h * 1024 + tid * 16, (char*)wol + tid * 16);
  else if (tid < 128)
    async16((const char*)wo12G + 8192 + (size_t)h * 1024 + (tid - 64) * 16,
            (char*)wol + 1024 + (tid - 64) * 16);
#pragma unroll
  for (int j = 0; j < 4; ++j) {
    const int r0 = wave * 32 + j * 8;
    async16(Ag + (size_t)(r0 + srow) * 320 + scol, &AsB[0][r0 * 64]);
    async16(Bg + (size_t)(r0 + srow) * 320 + scol, &BsB[0][r0 * 64]);
  }
  __syncthreads();   // implicit vmcnt(0): buf 0 + adjB + wol ready

#pragma unroll
  for (int t = 0; t < 5; ++t) {
    const f16* As = AsB[t & 1];
    const f16* Bs = BsB[t & 1];
    if (t < 4) {
      const int kn = (t + 1) * 64;
      f16* An = AsB[(t + 1) & 1];
      f16* Bn = BsB[(t + 1) & 1];
#pragma unroll
      for (int j = 0; j < 4; ++j) {
        const int r0 = wave * 32 + j * 8;
        async16(Ag + (size_t)(r0 + srow) * 320 + kn + scol, &An[r0 * 64]);
        async16(Bg + (size_t)(r0 + srow) * 320 + kn + scol, &Bn[r0 * 64]);
      }
    }
#pragma unroll
    for (int s = 0; s < 2; ++s) {
      const int sq = ((s * 4 + quad) ^ l7) * 8;
      f16x8 af[8], bf[4];
#pragma unroll
      for (int mt = 0; mt < 8; ++mt)
        af[mt] = *(const f16x8*)&As[(wm * 128 + mt * 16 + lrow) * 64 + sq];
#pragma unroll
      for (int nt = 0; nt < 4; ++nt)
        bf[nt] = *(const f16x8*)&Bs[(wn * 64 + nt * 16 + lrow) * 64 + sq];
#pragma unroll
      for (int mt = 0; mt < 8; ++mt)
#pragma unroll
        for (int nt = 0; nt < 4; ++nt)
          acc[mt][nt] = __builtin_amdgcn_mfma_f32_16x16x32_f16(af[mt], bf[nt], acc[mt][nt], 0, 0, 0);
    }
    __syncthreads();  // drains prefetch (after compute) + protects buffer reuse
  }

  // ---- epilogue 1: Wh -> LDS (transposed, swizzled) + e1/e2 dots ----
  float a1v[4], a2v[4];
#pragma unroll
  for (int nt = 0; nt < 4; ++nt) {
    const int o = wn * 64 + nt * 16 + lrow;
    a1v[nt] = ah[h * 512 + o];
    a2v[nt] = ah[h * 512 + 256 + o];
  }
#pragma unroll
  for (int mt = 0; mt < 8; ++mt) {
    const int n0 = wm * 128 + mt * 16 + quad * 4;
    const int q16 = n0 >> 3;             // 16B chunk index
    const int hoff = (n0 & 4) ? 8 : 0;   // 8B half within chunk
    float s1[4] = {0.f, 0.f, 0.f, 0.f}, s2[4] = {0.f, 0.f, 0.f, 0.f};
#pragma unroll
    for (int nt = 0; nt < 4; ++nt) {
      const int o = wn * 64 + nt * 16 + lrow;
      f16x4 v;
#pragma unroll
      for (int r = 0; r < 4; ++r) {
        v[r] = (f16)acc[mt][nt][r];
        s1[r] += acc[mt][nt][r] * a1v[nt];
        s2[r] += acc[mt][nt][r] * a2v[nt];
      }
      *(f16x4*)(WhB + o * 512 + ((q16 ^ (o & 7)) * 16 + hoff)) = v;
    }
#pragma unroll
    for (int r = 0; r < 4; ++r)
#pragma unroll
      for (int m = 1; m < 16; m <<= 1) {
        s1[r] += __shfl_xor(s1[r], m);
        s2[r] += __shfl_xor(s2[r], m);
      }
    if (lrow == 0) {
#pragma unroll
      for (int r = 0; r < 4; ++r) {
        atomicAdd(&e1f[n0 + r], s1[r]);
        atomicAdd(&e2f[n0 + r], s2[r]);
      }
    }
  }
  __syncthreads();

  // ---- phase 2: barrier-free register softmax + PV per wave ----
  float4 e2q = *(const float4*)&e2f[lane * 4];
  float e2m = fmaxf(fmaxf(e2q.x, e2q.y), fmaxf(e2q.z, e2q.w));
#pragma unroll
  for (int m = 1; m < 64; m <<= 1) e2m = fmaxf(e2m, __shfl_xor(e2m, m));

  const int nb0 = wave * 32;
  const float er0 = e1f[nb0 + lrow];
  const float er1 = e1f[nb0 + 16 + lrow];
  float sh0 = er0 + e2m; sh0 = sh0 > 0.f ? sh0 : 0.2f * sh0;
  float sh1 = er1 + e2m; sh1 = sh1 > 0.f ? sh1 : 0.2f * sh1;
  u64 aw0[4], aw1[4];
#pragma unroll
  for (int q = 0; q < 4; ++q) {
    aw0[q] = adjB[(nb0 + lrow) * 4 + q];
    aw1[q] = adjB[(nb0 + 16 + lrow) * 4 + q];
  }

  f16x8 p0[8], p1[8];
  float ss0 = 0.f, ss1 = 0.f;
#pragma unroll
  for (int k0 = 0; k0 < 8; ++k0) {
    const float* e2p = &e2f[k0 * 32 + quad * 8];
    float4 ea = *(const float4*)e2p;
    float4 eb = *(const float4*)(e2p + 4);
    unsigned int b0 = (unsigned int)(aw0[k0 >> 1] >> ((k0 & 1) * 32 + quad * 8)) & 0xFFu;
    unsigned int b1 = (unsigned int)(aw1[k0 >> 1] >> ((k0 & 1) * 32 + quad * 8)) & 0xFFu;
    float e2arr[8] = {ea.x, ea.y, ea.z, ea.w, eb.x, eb.y, eb.z, eb.w};
    f16x8 q0, q1;
#pragma unroll
    for (int j = 0; j < 8; ++j) {
      float v = er0 + e2arr[j]; v = v > 0.f ? v : 0.2f * v;
      float p = (b0 >> j) & 1 ? __expf(v - sh0) : 0.f;
      ss0 += p; q0[j] = (f16)p;
      v = er1 + e2arr[j]; v = v > 0.f ? v : 0.2f * v;
      p = (b1 >> j) & 1 ? __expf(v - sh1) : 0.f;
      ss1 += p; q1[j] = (f16)p;
    }
    p0[k0] = q0; p1[k0] = q1;
  }
  ss0 += __shfl_xor(ss0, 16); ss0 += __shfl_xor(ss0, 32);
  ss1 += __shfl_xor(ss1, 16); ss1 += __shfl_xor(ss1, 32);
  const float rs0 = 1.f / ss0, rs1 = 1.f / ss1;
  const float pm0 = npm[b * 256 + nb0 + lrow];
  const float pm1 = npm[b * 256 + nb0 + 16 + lrow];
  f16* h1b0 = &h1[(size_t)(b * 256 + nb0 + lrow) * 2048 + h * 256];
  f16* h1b1 = &h1[(size_t)(b * 256 + nb0 + 16 + lrow) * 2048 + h * 256];
  const char* wp = WhB + (size_t)lrow * 512;   // o = of*16 + lrow -> +of*8192B

  float e12p0 = 0.f, e22p0 = 0.f, e12p1 = 0.f, e22p1 = 0.f;
#pragma unroll 4
  for (int of = 0; of < 16; ++of) {
    f32x4 c0 = {}, c1 = {};
    const char* wo = wp + of * 8192;
#pragma unroll
    for (int k0 = 0; k0 < 8; ++k0) {
      f16x8 af = *(const f16x8*)(wo + (((k0 * 4 + quad) ^ l7) * 16));
      c0 = __builtin_amdgcn_mfma_f32_16x16x32_f16(af, p0[k0], c0, 0, 0, 0);
      c1 = __builtin_amdgcn_mfma_f32_16x16x32_f16(af, p1[k0], c1, 0, 0, 0);
    }
    const int o0 = of * 16 + quad * 4;
    f16x4 s0, s1;
#pragma unroll
    for (int r = 0; r < 4; ++r) {
      float w1 = wol[o0 + r], w2 = wol[256 + o0 + r];
      float v = c0[r] * rs0;
      v = v > 0.f ? v : (__expf(v) - 1.f);
      float hv0 = v * pm0;
      s0[r] = (f16)hv0;
      e12p0 += hv0 * w1; e22p0 += hv0 * w2;
      v = c1[r] * rs1;
      v = v > 0.f ? v : (__expf(v) - 1.f);
      float hv1 = v * pm1;
      s1[r] = (f16)hv1;
      e12p1 += hv1 * w1; e22p1 += hv1 * w2;
    }
    *(f16x4*)(h1b0 + o0) = s0;
    *(f16x4*)(h1b1 + o0) = s1;
  }

  // reduce e12/e22 partials over quads (same n for all 4 quads) and accumulate
  e12p0 += __shfl_xor(e12p0, 16); e12p0 += __shfl_xor(e12p0, 32);
  e22p0 += __shfl_xor(e22p0, 16); e22p0 += __shfl_xor(e22p0, 32);
  e12p1 += __shfl_xor(e12p1, 16); e12p1 += __shfl_xor(e12p1, 32);
  e22p1 += __shfl_xor(e22p1, 16); e22p1 += __shfl_xor(e22p1, 32);
  if (lane < 16) {
    atomicAdd(&e12G[b * 256 + nb0 + lrow], e12p0);
    atomicAdd(&e22G[b * 256 + nb0 + lrow], e22p0);
    atomicAdd(&e12G[b * 256 + nb0 + 16 + lrow], e12p1);
    atomicAdd(&e22G[b * 256 + nb0 + 16 + lrow], e22p1);
  }
}

// ---------------- GEMM 2: FULL-K, tile 64x64, 4 blocks/CU, no e-epilogue ----------------
// M=8192, N=512, K=2048; 1D grid 1024 blocks (4/CU, 32KB LDS).
// XCD-aware decode: 8 bx-siblings of each A-panel on one XCD.
__global__ __launch_bounds__(256, 4) void k_gemm_sk(const f16* __restrict__ A,
                                                    const f16* __restrict__ BT,
                                                    f16* __restrict__ outW) {
  __shared__ f16 As[64 * 64];
  __shared__ f16 Bs[64 * 64];
  const int bid = blockIdx.x;
  const int xcd = bid & 7, j = bid >> 3;    // j < 128
  const int bx = j & 7;
  const int by = xcd * 16 + (j >> 3);       // by < 128
  const int tid = threadIdx.x;
  const int wave = tid >> 6, lane = tid & 63;
  const int wm = wave >> 1, wn = wave & 1;
  const int lrow = lane & 15, quad = lane >> 4;
  const int srow = lane >> 3;
  const int scol = ((lane & 7) ^ (lane >> 3)) * 8;
  const int l7 = lrow & 7;

  f32x4 acc[2][2] = {};
  const f16* Ag = A + (size_t)by * 64 * 2048;
  const f16* Bg = BT + (size_t)bx * 64 * 2048;

  for (int k0 = 0; k0 < 2048; k0 += 64) {
    __syncthreads();
#pragma unroll
    for (int j2 = 0; j2 < 2; ++j2) {
      const int r0 = wave * 16 + j2 * 8;
      async16(Ag + (size_t)(r0 + srow) * 2048 + k0 + scol, &As[r0 * 64]);
      async16(Bg + (size_t)(r0 + srow) * 2048 + k0 + scol, &Bs[r0 * 64]);
    }
    __syncthreads();
#pragma unroll
    for (int s = 0; s < 2; ++s) {
      const int sq = ((s * 4 + quad) ^ l7) * 8;
      f16x8 af[2], bf[2];
#pragma unroll
      for (int t = 0; t < 2; ++t)
        af[t] = *(const f16x8*)&As[(wm * 32 + t * 16 + lrow) * 64 + sq];
#pragma unroll
      for (int t = 0; t < 2; ++t)
        bf[t] = *(const f16x8*)&Bs[(wn * 32 + t * 16 + lrow) * 64 + sq];
#pragma unroll
      for (int mt = 0; mt < 2; ++mt)
#pragma unroll
        for (int nt = 0; nt < 2; ++nt)
          acc[mt][nt] = __builtin_amdgcn_mfma_f32_16x16x32_f16(af[mt], bf[nt], acc[mt][nt], 0, 0, 0);
    }
  }

  const int b = (by * 64) >> 8;
  const int nbase0 = (by * 64) & 255;
#pragma unroll
  for (int mt = 0; mt < 2; ++mt) {
    const int nb = nbase0 + wm * 32 + mt * 16 + quad * 4;
#pragma unroll
    for (int nt = 0; nt < 2; ++nt) {
      const int gc = bx * 64 + wn * 32 + nt * 16 + lrow;
      f16x4 v;
#pragma unroll
      for (int r = 0; r < 4; ++r) v[r] = (f16)acc[mt][nt][r];
      *(f16x4*)&outW[((size_t)b * 512 + gc) * 256 + nb] = v;
    }
  }
}

#define PSTRIDE 264

// ---------------- fused attention layer 2 ----------------
// 1D grid 512: bid = xcd + 8*nt0 + 32*inner; pair = inner*8+xcd; oh = pair>>5, b = pair&31.
// Single full-K Wh2 buffer. A-fragment k0=0 loads hoisted before P-build.
__global__ __launch_bounds__(256, 4) void k_attn2(
    const f16* __restrict__ Wh2, const float* __restrict__ e1g, const float* __restrict__ e2g,
    const u64* __restrict__ adjG, const float* __restrict__ npm, float* __restrict__ out) {
  int bid = blockIdx.x;
  int nt0 = (bid >> 3) & 3;
  int pair = (bid >> 5) * 8 + (bid & 7);
  int oh = pair >> 5, b = pair & 31;
  int n0 = nt0 * 64;
  __shared__ f16 P[64 * PSTRIDE];
  int tid = threadIdx.x;
  int wave = tid >> 6, lane = tid & 63;
  int lrow = lane & 15, quad = lane >> 4;

  // prefetch A fragments for k0=0 (independent of P) — issue before softmax
  const f16* Ag = Wh2 + ((size_t)b * 512 + oh * 128) * 256;
  f16x8 afp[2];
#pragma unroll
  for (int mt = 0; mt < 2; ++mt) {
    size_t off = (size_t)(wave * 32 + mt * 16 + lrow) * 256 + quad * 8;
    afp[mt] = *(const f16x8*)&Ag[off];
  }

  float4 e2v = *(const float4*)&e2g[b * 256 + lane * 4];
  float e2m = fmaxf(fmaxf(e2v.x, e2v.y), fmaxf(e2v.z, e2v.w));
#pragma unroll
  for (int m = 1; m < 64; m <<= 1) e2m = fmaxf(e2m, __shfl_xor(e2m, m));
#pragma unroll 4
  for (int i = 0; i < 16; ++i) {
    int row = i * 4 + wave;
    int gn = b * 256 + n0 + row;
    float er = e1g[b * 256 + n0 + row];
    float sh = er + e2m;
    sh = sh > 0.f ? sh : 0.2f * sh;
    u64 word = adjG[(size_t)gn * 4 + (lane >> 4)];
    unsigned int bits = (unsigned int)(word >> ((lane & 15) * 4)) & 0xFu;
    float p0, p1, p2, p3;
    {
      float v = er + e2v.x; v = v > 0.f ? v : 0.2f * v;
      p0 = bits & 1 ? __expf(v - sh) : 0.f;
      v = er + e2v.y; v = v > 0.f ? v : 0.2f * v;
      p1 = bits & 2 ? __expf(v - sh) : 0.f;
      v = er + e2v.z; v = v > 0.f ? v : 0.2f * v;
      p2 = bits & 4 ? __expf(v - sh) : 0.f;
      v = er + e2v.w; v = v > 0.f ? v : 0.2f * v;
      p3 = bits & 8 ? __expf(v - sh) : 0.f;
    }
    float sm = p0 + p1 + p2 + p3;
#pragma unroll
    for (int m = 1; m < 64; m <<= 1) sm += __shfl_xor(sm, m);
    float rs = 1.f / sm;
    f16x4 pw;
    pw[0] = (f16)(p0 * rs); pw[1] = (f16)(p1 * rs);
    pw[2] = (f16)(p2 * rs); pw[3] = (f16)(p3 * rs);
    *(f16x4*)&P[row * PSTRIDE + lane * 4] = pw;
  }
  __syncthreads();

  f32x4 acc[2][4] = {};
#pragma unroll
  for (int kk = 0; kk < 8; ++kk) {
    const int k0 = kk * 32;
    f16x8 af[2], bf[4];
#pragma unroll
    for (int mt = 0; mt < 2; ++mt) {
      if (kk == 0) {
        af[mt] = afp[mt];
      } else {
        size_t off = (size_t)(wave * 32 + mt * 16 + lrow) * 256 + k0 + quad * 8;
        af[mt] = *(const f16x8*)&Ag[off];
      }
    }
#pragma unroll
    for (int nt = 0; nt < 4; ++nt)
      bf[nt] = *(const f16x8*)&P[(nt * 16 + lrow) * PSTRIDE + k0 + quad * 8];
#pragma unroll
    for (int mt = 0; mt < 2; ++mt)
#pragma unroll
      for (int nt = 0; nt < 4; ++nt)
        acc[mt][nt] = __builtin_amdgcn_mfma_f32_16x16x32_f16(af[mt], bf[nt], acc[mt][nt], 0, 0, 0);
  }
#pragma unroll
  for (int nt = 0; nt < 4; ++nt) {
    int nloc = nt * 16 + lrow;
    int gn = b * 256 + n0 + nloc;
    float pm = npm[gn];
#pragma unroll
    for (int mt = 0; mt < 2; ++mt) {
      int o0 = oh * 128 + wave * 32 + mt * 16 + quad * 4;
      float4 st;
      float v0 = acc[mt][nt][0] * pm;
      float v1 = acc[mt][nt][1] * pm;
      float v2 = acc[mt][nt][2] * pm;
      float v3 = acc[mt][nt][3] * pm;
      st.x = v0 > 0.f ? v0 : (__expf(v0) - 1.f);
      st.y = v1 > 0.f ? v1 : (__expf(v1) - 1.f);
      st.z = v2 > 0.f ? v2 : (__expf(v2) - 1.f);
      st.w = v3 > 0.f ? v3 : (__expf(v3) - 1.f);
      *(float4*)&out[(size_t)gn * 512 + o0] = st;
    }
  }
}

extern "C" void kernel_launch(void* const* d_in, const int* in_sizes, int n_in,
                              void* d_out, int out_size, void* d_ws, size_t ws_size,
                              hipStream_t stream) {
  (void)in_sizes; (void)n_in; (void)out_size; (void)ws_size;
  const int*   fea   = (const int*)d_in[0];
  const int*   adj   = (const int*)d_in[1];
  const float* npm   = (const float*)d_in[2];
  const float* embed = (const float*)d_in[3];
  const float* Whd   = (const float*)d_in[4];
  const float* ah    = (const float*)d_in[5];
  const float* Wo    = (const float*)d_in[6];
  const float* ao    = (const float*)d_in[7];
  float* out = (float*)d_out;

  char* ws = (char*)d_ws;
  f16* x16  = (f16*)ws;  ws += (size_t)8192 * 320 * 2;
  f16* WcT  = (f16*)ws;  ws += (size_t)2048 * 320 * 2;
  f16* WoT  = (f16*)ws;  ws += (size_t)512 * 2048 * 2;
  f16* h1   = (f16*)ws;  ws += (size_t)8192 * 2048 * 2;          // [bn][h*256+o]
  f16* Wh2  = (f16*)ws;  ws += (size_t)32 * 512 * 256 * 2;       // full-K layer-2 result
  float* e12 = (float*)ws; ws += (size_t)8192 * 4;
  float* e22 = (float*)ws; ws += (size_t)8192 * 4;
  u64* adjG = (u64*)ws;  ws += (size_t)8192 * 4 * 8;             // bit-packed adj
  float* wo12G = (float*)ws; ws += (size_t)2 * 2048 * 4;         // wo1|wo2

  // k_prep zeroes e12/e22 in-kernel; packs adjG; computes wo12
  k_prep<<<3080, 256, 0, stream>>>(fea, embed, Whd, Wo, adj, ao, x16, WcT, WoT, e12, adjG, wo12G);

  k_l1<<<256, 512, 143360, stream>>>(x16, WcT, ah, adjG, npm, wo12G, h1, e12, e22);

  k_gemm_sk<<<1024, 256, 0, stream>>>(h1, WoT, Wh2);
  k_attn2<<<512, 256, 0, stream>>>(Wh2, e12, e22, adjG, npm, out);
}

// Round 15
// 167.510 us; speedup vs baseline: 1.0290x; 1.0290x over previous
//
#include <hip/hip_runtime.h>
#include <math.h>

// GAT forward: B=32 N=256 F=300(pad 320) O=256 H=8 OUT=512

typedef _Float16 f16;
typedef __attribute__((ext_vector_type(8))) _Float16 f16x8;
typedef __attribute__((ext_vector_type(4))) _Float16 f16x4;
typedef __attribute__((ext_vector_type(4))) float f32x4;
typedef unsigned long long u64;

__device__ __forceinline__ void async16(const void* g, void* lds) {
  __builtin_amdgcn_global_load_lds(
      (const __attribute__((address_space(1))) void*)g,
      (__attribute__((address_space(3))) void*)lds, 16, 0, 0);
}

// ---------------- fused prep: x16 + WcT + WoT + e-zero + adj bit-pack ----------------
// blocks [0,1280): x16; [1280,1920): WcT + e-zero; [1920,2944): WoT; [2944,3072): adjG.
__global__ __launch_bounds__(256) void k_prep(const int* __restrict__ fea,
                                              const float* __restrict__ embed,
                                              const float* __restrict__ Whd,
                                              const float* __restrict__ Wo,
                                              const int* __restrict__ adj,
                                              f16* __restrict__ x16,
                                              f16* __restrict__ WcT,
                                              f16* __restrict__ WoT,
                                              float* __restrict__ e_all,
                                              u64* __restrict__ adjG) {
  int bid = blockIdx.x, tid = threadIdx.x;
  if (bid < 1280) {
    // x16: 8192 rows x 40 chunks of 8 f16 (16B store per thread); float4 loads
    int idx = bid * 256 + tid;          // < 327680
    int row = idx / 40, c = idx % 40;
    int tok = fea[row];
    const float* eb = embed + (size_t)tok * 300;
    f16x8 v;
    if (c < 37) {
      float4 f0 = *(const float4*)&eb[c * 8];
      float4 f1 = *(const float4*)&eb[c * 8 + 4];
      v[0] = (f16)f0.x; v[1] = (f16)f0.y; v[2] = (f16)f0.z; v[3] = (f16)f0.w;
      v[4] = (f16)f1.x; v[5] = (f16)f1.y; v[6] = (f16)f1.z; v[7] = (f16)f1.w;
    } else {
#pragma unroll
      for (int j = 0; j < 8; ++j) {
        int t = c * 8 + j;
        v[j] = (f16)((t < 300) ? eb[t] : 0.f);
      }
    }
    *(f16x8*)&x16[(size_t)row * 320 + c * 8] = v;
  } else if (bid < 1920) {
    int r = bid - 1280;                 // < 640
    // zero e12/e22 accumulators (16384 floats, contiguous)
    int zi = r * 256 + tid;
    if (zi < 16384) e_all[zi] = 0.f;
    // WcT: W[h][t<300][o<256] -> WcT[(h*256+o)*320 + t]
    __shared__ float tile[32][33];
    int bx = r % 10, q0 = r / 10;
    int by = q0 % 8, h = q0 / 8;
    int c = tid & 31, q = tid >> 5;
#pragma unroll
    for (int i = 0; i < 4; ++i) {
      int tt = q + i * 8;
      int t = bx * 32 + tt;
      float v = (t < 300) ? Whd[((size_t)h * 300 + t) * 256 + by * 32 + c] : 0.f;
      tile[tt][c] = v;
    }
    __syncthreads();
#pragma unroll
    for (int i = 0; i < 4; ++i) {
      int oo = q + i * 8;
      int gc = h * 256 + by * 32 + oo;
      WcT[(size_t)gc * 320 + bx * 32 + c] = (f16)tile[c][oo];
    }
  } else if (bid < 2944) {
    int r = bid - 1920;                 // < 1024
    // WoT: W[k<2048][o2<512] -> WoT[o2*2048 + k]
    __shared__ float tile[32][33];
    int bx = r % 64, by = r / 64;
    int c = tid & 31, q = tid >> 5;
#pragma unroll
    for (int i = 0; i < 4; ++i) {
      int kk = q + i * 8;
      tile[kk][c] = Wo[((size_t)bx * 32 + kk) * 512 + by * 32 + c];
    }
    __syncthreads();
#pragma unroll
    for (int i = 0; i < 4; ++i) {
      int oo = q + i * 8;
      WoT[((size_t)by * 32 + oo) * 2048 + bx * 32 + c] = (f16)tile[c][oo];
    }
  } else {
    // adjG: adj[8192 rows][256] int -> 4 u64 bitmasks per row
    int r = bid - 2944;                 // < 128
    int wv = tid >> 6, ln = tid & 63;
    int row = r * 64 + wv * 16;
    const int* ar = adj + (size_t)row * 256;
#pragma unroll 4
    for (int i = 0; i < 16; ++i, ar += 256) {
      u64 m0 = __ballot(ar[ln] != 0);
      u64 m1 = __ballot(ar[64 + ln] != 0);
      u64 m2 = __ballot(ar[128 + ln] != 0);
      u64 m3 = __ballot(ar[192 + ln] != 0);
      if (ln == 0) {
        u64* d = &adjG[(size_t)(row + i) * 4];
        d[0] = m0; d[1] = m1; d[2] = m2; d[3] = m3;
      }
    }
  }
}

// ---------------- fused layer 1: GEMM1 + e-dots + reg-softmax + PV + elu ----------------
// One block per (b,h); 512 threads (8 waves); dynamic LDS 141312 B; 1 block/CU.
// Phase 2 is barrier-free: P lives in registers in MFMA B-fragment layout.
__global__ __launch_bounds__(512, 1) void k_l1(
    const f16* __restrict__ x16, const f16* __restrict__ WcT,
    const float* __restrict__ ah, const u64* __restrict__ adjG,
    const float* __restrict__ npm, f16* __restrict__ h1) {
  extern __shared__ __align__(16) char smem[];
  f16* AsB[2] = {(f16*)smem, (f16*)(smem + 65536)};           // [256][64] each
  f16* BsB[2] = {(f16*)(smem + 32768), (f16*)(smem + 98304)}; // [256][64] each
  char* WhB = smem;                           // Wh bytes: [o][256 f16] chunk-swz
  u64* adjB = (u64*)(smem + 131072);          // [256][4]
  float* e1f = (float*)(smem + 139264);       // [256]
  float* e2f = (float*)(smem + 140288);       // [256]

  const int bid = blockIdx.x;
  const int h = (bid >> 3) & 7;
  const int b = (bid & 7) * 4 + (bid >> 6);
  const int tid = threadIdx.x;
  const int wave = tid >> 6, lane = tid & 63;
  const int wm = wave >> 2, wn = wave & 3;
  const int lrow = lane & 15, quad = lane >> 4;
  const int srow = lane >> 3;
  const int scol = ((lane & 7) ^ (lane >> 3)) * 8;
  const int l7 = lrow & 7;

  if (tid < 256) e1f[tid] = 0.f;
  else e2f[tid - 256] = 0.f;

  // ---- phase 1: Wh = x16[b] @ WcT[h]^T into registers (2-stage dbuf) ----
  f32x4 acc[8][4] = {};   // n = wm*128+mt*16+quad*4+r ; o = wn*64+nt*16+lrow
  const f16* Ag = x16 + (size_t)b * 256 * 320;
  const f16* Bg = WcT + (size_t)h * 256 * 320;

  // prologue: stage K-step 0 into buf 0 + adjB (8KB, 16B/thread)
  async16((const char*)adjG + (size_t)b * 8192 + tid * 16, (char*)adjB + tid * 16);
#pragma unroll
  for (int j = 0; j < 4; ++j) {
    const int r0 = wave * 32 + j * 8;
    async16(Ag + (size_t)(r0 + srow) * 320 + scol, &AsB[0][r0 * 64]);
    async16(Bg + (size_t)(r0 + srow) * 320 + scol, &BsB[0][r0 * 64]);
  }
  __syncthreads();   // implicit vmcnt(0): buf 0 + adjB ready

#pragma unroll
  for (int t = 0; t < 5; ++t) {
    const f16* As = AsB[t & 1];
    const f16* Bs = BsB[t & 1];
    if (t < 4) {
      const int kn = (t + 1) * 64;
      f16* An = AsB[(t + 1) & 1];
      f16* Bn = BsB[(t + 1) & 1];
#pragma unroll
      for (int j = 0; j < 4; ++j) {
        const int r0 = wave * 32 + j * 8;
        async16(Ag + (size_t)(r0 + srow) * 320 + kn + scol, &An[r0 * 64]);
        async16(Bg + (size_t)(r0 + srow) * 320 + kn + scol, &Bn[r0 * 64]);
      }
    }
#pragma unroll
    for (int s = 0; s < 2; ++s) {
      const int sq = ((s * 4 + quad) ^ l7) * 8;
      f16x8 af[8], bf[4];
#pragma unroll
      for (int mt = 0; mt < 8; ++mt)
        af[mt] = *(const f16x8*)&As[(wm * 128 + mt * 16 + lrow) * 64 + sq];
#pragma unroll
      for (int nt = 0; nt < 4; ++nt)
        bf[nt] = *(const f16x8*)&Bs[(wn * 64 + nt * 16 + lrow) * 64 + sq];
#pragma unroll
      for (int mt = 0; mt < 8; ++mt)
#pragma unroll
        for (int nt = 0; nt < 4; ++nt)
          acc[mt][nt] = __builtin_amdgcn_mfma_f32_16x16x32_f16(af[mt], bf[nt], acc[mt][nt], 0, 0, 0);
    }
    __syncthreads();  // drains prefetch (after compute) + protects buffer reuse
  }

  // ---- epilogue 1: Wh -> LDS (transposed, swizzled) + e1/e2 dots ----
  float a1v[4], a2v[4];
#pragma unroll
  for (int nt = 0; nt < 4; ++nt) {
    const int o = wn * 64 + nt * 16 + lrow;
    a1v[nt] = ah[h * 512 + o];
    a2v[nt] = ah[h * 512 + 256 + o];
  }
#pragma unroll
  for (int mt = 0; mt < 8; ++mt) {
    const int n0 = wm * 128 + mt * 16 + quad * 4;
    const int q16 = n0 >> 3;             // 16B chunk index
    const int hoff = (n0 & 4) ? 8 : 0;   // 8B half within chunk
    float s1[4] = {0.f, 0.f, 0.f, 0.f}, s2[4] = {0.f, 0.f, 0.f, 0.f};
#pragma unroll
    for (int nt = 0; nt < 4; ++nt) {
      const int o = wn * 64 + nt * 16 + lrow;
      f16x4 v;
#pragma unroll
      for (int r = 0; r < 4; ++r) {
        v[r] = (f16)acc[mt][nt][r];
        s1[r] += acc[mt][nt][r] * a1v[nt];
        s2[r] += acc[mt][nt][r] * a2v[nt];
      }
      *(f16x4*)(WhB + o * 512 + ((q16 ^ (o & 7)) * 16 + hoff)) = v;
    }
#pragma unroll
    for (int r = 0; r < 4; ++r)
#pragma unroll
      for (int m = 1; m < 16; m <<= 1) {
        s1[r] += __shfl_xor(s1[r], m);
        s2[r] += __shfl_xor(s2[r], m);
      }
    if (lrow == 0) {
#pragma unroll
      for (int r = 0; r < 4; ++r) {
        atomicAdd(&e1f[n0 + r], s1[r]);
        atomicAdd(&e2f[n0 + r], s2[r]);
      }
    }
  }
  __syncthreads();

  // ---- phase 2: barrier-free register softmax + PV per wave ----
  float4 e2q = *(const float4*)&e2f[lane * 4];
  float e2m = fmaxf(fmaxf(e2q.x, e2q.y), fmaxf(e2q.z, e2q.w));
#pragma unroll
  for (int m = 1; m < 64; m <<= 1) e2m = fmaxf(e2m, __shfl_xor(e2m, m));

  const int nb0 = wave * 32;
  const float er0 = e1f[nb0 + lrow];
  const float er1 = e1f[nb0 + 16 + lrow];
  float sh0 = er0 + e2m; sh0 = sh0 > 0.f ? sh0 : 0.2f * sh0;
  float sh1 = er1 + e2m; sh1 = sh1 > 0.f ? sh1 : 0.2f * sh1;
  u64 aw0[4], aw1[4];
#pragma unroll
  for (int q = 0; q < 4; ++q) {
    aw0[q] = adjB[(nb0 + lrow) * 4 + q];
    aw1[q] = adjB[(nb0 + 16 + lrow) * 4 + q];
  }

  f16x8 p0[8], p1[8];
  float ss0 = 0.f, ss1 = 0.f;
#pragma unroll
  for (int k0 = 0; k0 < 8; ++k0) {
    const float* e2p = &e2f[k0 * 32 + quad * 8];
    float4 ea = *(const float4*)e2p;
    float4 eb = *(const float4*)(e2p + 4);
    unsigned int b0 = (unsigned int)(aw0[k0 >> 1] >> ((k0 & 1) * 32 + quad * 8)) & 0xFFu;
    unsigned int b1 = (unsigned int)(aw1[k0 >> 1] >> ((k0 & 1) * 32 + quad * 8)) & 0xFFu;
    float e2arr[8] = {ea.x, ea.y, ea.z, ea.w, eb.x, eb.y, eb.z, eb.w};
    f16x8 q0, q1;
#pragma unroll
    for (int j = 0; j < 8; ++j) {
      float v = er0 + e2arr[j]; v = v > 0.f ? v : 0.2f * v;
      float p = (b0 >> j) & 1 ? __expf(v - sh0) : 0.f;
      ss0 += p; q0[j] = (f16)p;
      v = er1 + e2arr[j]; v = v > 0.f ? v : 0.2f * v;
      p = (b1 >> j) & 1 ? __expf(v - sh1) : 0.f;
      ss1 += p; q1[j] = (f16)p;
    }
    p0[k0] = q0; p1[k0] = q1;
  }
  ss0 += __shfl_xor(ss0, 16); ss0 += __shfl_xor(ss0, 32);
  ss1 += __shfl_xor(ss1, 16); ss1 += __shfl_xor(ss1, 32);
  const float rs0 = 1.f / ss0, rs1 = 1.f / ss1;
  const float pm0 = npm[b * 256 + nb0 + lrow];
  const float pm1 = npm[b * 256 + nb0 + 16 + lrow];
  f16* h1b0 = &h1[(size_t)(b * 256 + nb0 + lrow) * 2048 + h * 256];
  f16* h1b1 = &h1[(size_t)(b * 256 + nb0 + 16 + lrow) * 2048 + h * 256];
  const char* wp = WhB + (size_t)lrow * 512;   // o = of*16 + lrow -> +of*8192B

#pragma unroll 4
  for (int of = 0; of < 16; ++of) {
    f32x4 c0 = {}, c1 = {};
    const char* wo = wp + of * 8192;
#pragma unroll
    for (int k0 = 0; k0 < 8; ++k0) {
      f16x8 af = *(const f16x8*)(wo + (((k0 * 4 + quad) ^ l7) * 16));
      c0 = __builtin_amdgcn_mfma_f32_16x16x32_f16(af, p0[k0], c0, 0, 0, 0);
      c1 = __builtin_amdgcn_mfma_f32_16x16x32_f16(af, p1[k0], c1, 0, 0, 0);
    }
    const int o0 = of * 16 + quad * 4;
    f16x4 s0, s1;
#pragma unroll
    for (int r = 0; r < 4; ++r) {
      float v = c0[r] * rs0;
      v = v > 0.f ? v : (__expf(v) - 1.f);
      s0[r] = (f16)(v * pm0);
      v = c1[r] * rs1;
      v = v > 0.f ? v : (__expf(v) - 1.f);
      s1[r] = (f16)(v * pm1);
    }
    *(f16x4*)(h1b0 + o0) = s0;
    *(f16x4*)(h1b1 + o0) = s1;
  }
}

// ---------------- GEMM 2: FULL-K, tile 64x64, 4 blocks/CU ----------------
// M=8192, N=512, K=2048; 1D grid 1024 blocks (4/CU, 32KB LDS).
// XCD-aware decode: 8 bx-siblings of each A-panel on one XCD.
// e12/e22 dots fused via f32 atomics.
__global__ __launch_bounds__(256, 4) void k_gemm_sk(const f16* __restrict__ A,
                                                    const f16* __restrict__ BT,
                                                    f16* __restrict__ outW,
                                                    const float* __restrict__ ao,
                                                    float* __restrict__ e12,
                                                    float* __restrict__ e22) {
  __shared__ f16 As[64 * 64];
  __shared__ f16 Bs[64 * 64];
  const int bid = blockIdx.x;
  const int xcd = bid & 7, j = bid >> 3;    // j < 128
  const int bx = j & 7;
  const int by = xcd * 16 + (j >> 3);       // by < 128
  const int tid = threadIdx.x;
  const int wave = tid >> 6, lane = tid & 63;
  const int wm = wave >> 1, wn = wave & 1;
  const int lrow = lane & 15, quad = lane >> 4;
  const int srow = lane >> 3;
  const int scol = ((lane & 7) ^ (lane >> 3)) * 8;
  const int l7 = lrow & 7;

  f32x4 acc[2][2] = {};
  const f16* Ag = A + (size_t)by * 64 * 2048;
  const f16* Bg = BT + (size_t)bx * 64 * 2048;

  for (int k0 = 0; k0 < 2048; k0 += 64) {
    __syncthreads();
#pragma unroll
    for (int j2 = 0; j2 < 2; ++j2) {
      const int r0 = wave * 16 + j2 * 8;
      async16(Ag + (size_t)(r0 + srow) * 2048 + k0 + scol, &As[r0 * 64]);
      async16(Bg + (size_t)(r0 + srow) * 2048 + k0 + scol, &Bs[r0 * 64]);
    }
    __syncthreads();
#pragma unroll
    for (int s = 0; s < 2; ++s) {
      const int sq = ((s * 4 + quad) ^ l7) * 8;
      f16x8 af[2], bf[2];
#pragma unroll
      for (int t = 0; t < 2; ++t)
        af[t] = *(const f16x8*)&As[(wm * 32 + t * 16 + lrow) * 64 + sq];
#pragma unroll
      for (int t = 0; t < 2; ++t)
        bf[t] = *(const f16x8*)&Bs[(wn * 32 + t * 16 + lrow) * 64 + sq];
#pragma unroll
      for (int mt = 0; mt < 2; ++mt)
#pragma unroll
        for (int nt = 0; nt < 2; ++nt)
          acc[mt][nt] = __builtin_amdgcn_mfma_f32_16x16x32_f16(af[mt], bf[nt], acc[mt][nt], 0, 0, 0);
    }
  }

  const int b = (by * 64) >> 8;
  const int nbase0 = (by * 64) & 255;
#pragma unroll
  for (int mt = 0; mt < 2; ++mt) {
    const int nb = nbase0 + wm * 32 + mt * 16 + quad * 4;
#pragma unroll
    for (int nt = 0; nt < 2; ++nt) {
      const int gc = bx * 64 + wn * 32 + nt * 16 + lrow;
      f16x4 v;
#pragma unroll
      for (int r = 0; r < 4; ++r) v[r] = (f16)acc[mt][nt][r];
      *(f16x4*)&outW[((size_t)b * 512 + gc) * 256 + nb] = v;
    }
  }

  // fused e12/e22 dots (from full-K f32 accumulators, pre-f16-rounding)
  float a1v[2], a2v[2];
#pragma unroll
  for (int nt = 0; nt < 2; ++nt) {
    const int gc = bx * 64 + wn * 32 + nt * 16 + lrow;
    a1v[nt] = ao[gc];
    a2v[nt] = ao[512 + gc];
  }
#pragma unroll
  for (int mt = 0; mt < 2; ++mt) {
    float s1[4] = {0.f, 0.f, 0.f, 0.f}, s2[4] = {0.f, 0.f, 0.f, 0.f};
#pragma unroll
    for (int nt = 0; nt < 2; ++nt)
#pragma unroll
      for (int r = 0; r < 4; ++r) {
        s1[r] += acc[mt][nt][r] * a1v[nt];
        s2[r] += acc[mt][nt][r] * a2v[nt];
      }
#pragma unroll
    for (int r = 0; r < 4; ++r)
#pragma unroll
      for (int m = 1; m < 16; m <<= 1) {
        s1[r] += __shfl_xor(s1[r], m);
        s2[r] += __shfl_xor(s2[r], m);
      }
    if (lrow == 0) {
      const int nb = nbase0 + wm * 32 + mt * 16 + quad * 4;
#pragma unroll
      for (int r = 0; r < 4; ++r) {
        atomicAdd(&e12[b * 256 + nb + r], s1[r]);
        atomicAdd(&e22[b * 256 + nb + r], s2[r]);
      }
    }
  }
}

#define PSTRIDE 264

// ---------------- fused attention layer 2 ----------------
// 1D grid 512: bid = xcd + 8*nt0 + 32*inner; pair = inner*8+xcd; oh = pair>>5, b = pair&31.
// Single full-K Wh2 buffer (no split-K halves, no add).
// A-fragment k0=0 loads hoisted BEFORE the P-build so L2 latency hides under softmax.
__global__ __launch_bounds__(256, 4) void k_attn2(
    const f16* __restrict__ Wh2, const float* __restrict__ e1g, const float* __restrict__ e2g,
    const u64* __restrict__ adjG, const float* __restrict__ npm, float* __restrict__ out) {
  int bid = blockIdx.x;
  int nt0 = (bid >> 3) & 3;
  int pair = (bid >> 5) * 8 + (bid & 7);
  int oh = pair >> 5, b = pair & 31;
  int n0 = nt0 * 64;
  __shared__ f16 P[64 * PSTRIDE];
  int tid = threadIdx.x;
  int wave = tid >> 6, lane = tid & 63;
  int lrow = lane & 15, quad = lane >> 4;

  // prefetch A fragments for k0=0 (independent of P) — issue before softmax
  const f16* Ag = Wh2 + ((size_t)b * 512 + oh * 128) * 256;
  f16x8 afp[2];
#pragma unroll
  for (int mt = 0; mt < 2; ++mt) {
    size_t off = (size_t)(wave * 32 + mt * 16 + lrow) * 256 + quad * 8;
    afp[mt] = *(const f16x8*)&Ag[off];
  }

  float4 e2v = *(const float4*)&e2g[b * 256 + lane * 4];
  float e2m = fmaxf(fmaxf(e2v.x, e2v.y), fmaxf(e2v.z, e2v.w));
#pragma unroll
  for (int m = 1; m < 64; m <<= 1) e2m = fmaxf(e2m, __shfl_xor(e2m, m));
#pragma unroll 4
  for (int i = 0; i < 16; ++i) {
    int row = i * 4 + wave;
    int gn = b * 256 + n0 + row;
    float er = e1g[b * 256 + n0 + row];
    float sh = er + e2m;
    sh = sh > 0.f ? sh : 0.2f * sh;
    u64 word = adjG[(size_t)gn * 4 + (lane >> 4)];
    unsigned int bits = (unsigned int)(word >> ((lane & 15) * 4)) & 0xFu;
    float p0, p1, p2, p3;
    {
      float v = er + e2v.x; v = v > 0.f ? v : 0.2f * v;
      p0 = bits & 1 ? __expf(v - sh) : 0.f;
      v = er + e2v.y; v = v > 0.f ? v : 0.2f * v;
      p1 = bits & 2 ? __expf(v - sh) : 0.f;
      v = er + e2v.z; v = v > 0.f ? v : 0.2f * v;
      p2 = bits & 4 ? __expf(v - sh) : 0.f;
      v = er + e2v.w; v = v > 0.f ? v : 0.2f * v;
      p3 = bits & 8 ? __expf(v - sh) : 0.f;
    }
    float sm = p0 + p1 + p2 + p3;
#pragma unroll
    for (int m = 1; m < 64; m <<= 1) sm += __shfl_xor(sm, m);
    float rs = 1.f / sm;
    f16x4 pw;
    pw[0] = (f16)(p0 * rs); pw[1] = (f16)(p1 * rs);
    pw[2] = (f16)(p2 * rs); pw[3] = (f16)(p3 * rs);
    *(f16x4*)&P[row * PSTRIDE + lane * 4] = pw;
  }
  __syncthreads();

  f32x4 acc[2][4] = {};
#pragma unroll
  for (int kk = 0; kk < 8; ++kk) {
    const int k0 = kk * 32;
    f16x8 af[2], bf[4];
#pragma unroll
    for (int mt = 0; mt < 2; ++mt) {
      if (kk == 0) {
        af[mt] = afp[mt];
      } else {
        size_t off = (size_t)(wave * 32 + mt * 16 + lrow) * 256 + k0 + quad * 8;
        af[mt] = *(const f16x8*)&Ag[off];
      }
    }
#pragma unroll
    for (int nt = 0; nt < 4; ++nt)
      bf[nt] = *(const f16x8*)&P[(nt * 16 + lrow) * PSTRIDE + k0 + quad * 8];
#pragma unroll
    for (int mt = 0; mt < 2; ++mt)
#pragma unroll
      for (int nt = 0; nt < 4; ++nt)
        acc[mt][nt] = __builtin_amdgcn_mfma_f32_16x16x32_f16(af[mt], bf[nt], acc[mt][nt], 0, 0, 0);
  }
#pragma unroll
  for (int nt = 0; nt < 4; ++nt) {
    int nloc = nt * 16 + lrow;
    int gn = b * 256 + n0 + nloc;
    float pm = npm[gn];
#pragma unroll
    for (int mt = 0; mt < 2; ++mt) {
      int o0 = oh * 128 + wave * 32 + mt * 16 + quad * 4;
      float4 st;
      float v0 = acc[mt][nt][0] * pm;
      float v1 = acc[mt][nt][1] * pm;
      float v2 = acc[mt][nt][2] * pm;
      float v3 = acc[mt][nt][3] * pm;
      st.x = v0 > 0.f ? v0 : (__expf(v0) - 1.f);
      st.y = v1 > 0.f ? v1 : (__expf(v1) - 1.f);
      st.z = v2 > 0.f ? v2 : (__expf(v2) - 1.f);
      st.w = v3 > 0.f ? v3 : (__expf(v3) - 1.f);
      *(float4*)&out[(size_t)gn * 512 + o0] = st;
    }
  }
}

extern "C" void kernel_launch(void* const* d_in, const int* in_sizes, int n_in,
                              void* d_out, int out_size, void* d_ws, size_t ws_size,
                              hipStream_t stream) {
  (void)in_sizes; (void)n_in; (void)out_size; (void)ws_size;
  const int*   fea   = (const int*)d_in[0];
  const int*   adj   = (const int*)d_in[1];
  const float* npm   = (const float*)d_in[2];
  const float* embed = (const float*)d_in[3];
  const float* Whd   = (const float*)d_in[4];
  const float* ah    = (const float*)d_in[5];
  const float* Wo    = (const float*)d_in[6];
  const float* ao    = (const float*)d_in[7];
  float* out = (float*)d_out;

  char* ws = (char*)d_ws;
  f16* x16  = (f16*)ws;  ws += (size_t)8192 * 320 * 2;
  f16* WcT  = (f16*)ws;  ws += (size_t)2048 * 320 * 2;
  f16* WoT  = (f16*)ws;  ws += (size_t)512 * 2048 * 2;
  f16* h1   = (f16*)ws;  ws += (size_t)8192 * 2048 * 2;          // [bn][h*256+o]
  f16* Wh2  = (f16*)ws;  ws += (size_t)32 * 512 * 256 * 2;       // full-K layer-2 result
  float* e12 = (float*)ws; ws += (size_t)8192 * 4;
  float* e22 = (float*)ws; ws += (size_t)8192 * 4;
  u64* adjG = (u64*)ws;  ws += (size_t)8192 * 4 * 8;             // bit-packed adj

  // k_prep zeroes e12/e22 (contiguous 16384 floats) in-kernel; packs adjG
  k_prep<<<3072, 256, 0, stream>>>(fea, embed, Whd, Wo, adj, x16, WcT, WoT, e12, adjG);

  k_l1<<<256, 512, 141312, stream>>>(x16, WcT, ah, adjG, npm, h1);

  k_gemm_sk<<<1024, 256, 0, stream>>>(h1, WoT, Wh2, ao, e12, e22);
  k_attn2<<<512, 256, 0, stream>>>(Wh2, e12, e22, adjG, npm, out);
}